// Round 7
// baseline (95.043 us; speedup 1.0000x reference)
//
#include <hip/hip_runtime.h>

namespace {
constexpr int D = 8;
constexpr int B = 2;
constexpr int N = 2048;
constexpr long long NN = (long long)N * N;
constexpr float ALPHA_P = 0.95f;   // pre-trace decay
constexpr float ALPHA_D = 0.90f;   // post-trace decay
constexpr float WMAX = 1.0f;
}

typedef float f32x4 __attribute__((ext_vector_type(4)));

// One block per presynaptic row e; 256 threads; o = it*1024 + tid*4.
// Issue-pipelined version of R6: gating scalars -> predicates -> ALL gated
// dmap/W/A/xbp loads for BOTH iterations issued back-to-back -> FMAs ->
// dense full-line stores. Gated loads are bit-exact (skipped values only
// ever multiply exact zeros).
__global__ __launch_bounds__(256) void stdp_main(
    const float* __restrict__ Xd,
    const float* __restrict__ Xpost,
    const float* __restrict__ xbar_pre,
    const float* __restrict__ xbar_post,
    const float* __restrict__ W,
    const float* __restrict__ dmap,
    const float* __restrict__ A_p,
    const float* __restrict__ A_d,
    float* __restrict__ W_prev,
    float* __restrict__ W_new,
    float* __restrict__ xbar_pre_new,
    float* __restrict__ xbar_post_new)
{
    const int e = blockIdx.x;
    const int tid = (int)threadIdx.x;
    const long long row = (long long)e * N;
    const int o0 = tid * 4;          // iteration 0 column base
    const int o1 = 1024 + tid * 4;   // iteration 1 column base

    // ---- 1. gating scalars first (L2-resident row reads) ----
    float xs0[D], xs1[D];
#pragma unroll
    for (int d = 0; d < D; ++d) {
        xs0[d] = Xd[(size_t)(d * B + 0) * N + e];
        xs1[d] = Xd[(size_t)(d * B + 1) * N + e];
    }

    // ---- 2. post-spike vectors for both iterations ----
    const f32x4 xpo0a = *reinterpret_cast<const f32x4*>(Xpost + o0);
    const f32x4 xpo1a = *reinterpret_cast<const f32x4*>(Xpost + N + o0);
    const f32x4 xpo0b = *reinterpret_cast<const f32x4*>(Xpost + o1);
    const f32x4 xpo1b = *reinterpret_cast<const f32x4*>(Xpost + N + o1);

    // ---- 3. predicates ----
    unsigned um = 0;
#pragma unroll
    for (int d = 0; d < D; ++d)
        if (xs0[d] != 0.0f || xs1[d] != 0.0f) um |= 1u << d;

    const bool grpA = (xpo0a[0] != 0.0f) || (xpo0a[1] != 0.0f) ||
                      (xpo0a[2] != 0.0f) || (xpo0a[3] != 0.0f) ||
                      (xpo1a[0] != 0.0f) || (xpo1a[1] != 0.0f) ||
                      (xpo1a[2] != 0.0f) || (xpo1a[3] != 0.0f);
    const bool grpB = (xpo0b[0] != 0.0f) || (xpo0b[1] != 0.0f) ||
                      (xpo0b[2] != 0.0f) || (xpo0b[3] != 0.0f) ||
                      (xpo1b[0] != 0.0f) || (xpo1b[1] != 0.0f) ||
                      (xpo1b[2] != 0.0f) || (xpo1b[3] != 0.0f);

    // ---- 4. issue ALL gated dmap loads (both iterations, 16 loads) ----
    f32x4 mA[D], mB[D];
#pragma unroll
    for (int d = 0; d < D; ++d) {
        const bool act = (um >> d) & 1u;
        mA[d] = (f32x4){0.f, 0.f, 0.f, 0.f};
        if (grpA || act)
            mA[d] = *reinterpret_cast<const f32x4*>(dmap + (size_t)d * NN + row + o0);
        mB[d] = (f32x4){0.f, 0.f, 0.f, 0.f};
        if (grpB || act)
            mB[d] = *reinterpret_cast<const f32x4*>(dmap + (size_t)d * NN + row + o1);
    }

    // ---- 5. W / A / xbar_post loads (both iterations) ----
    const f32x4 w0a = __builtin_nontemporal_load(reinterpret_cast<const f32x4*>(W + row + o0));
    const f32x4 w1a = __builtin_nontemporal_load(reinterpret_cast<const f32x4*>(W + NN + row + o0));
    const f32x4 w0b = __builtin_nontemporal_load(reinterpret_cast<const f32x4*>(W + row + o1));
    const f32x4 w1b = __builtin_nontemporal_load(reinterpret_cast<const f32x4*>(W + NN + row + o1));

    f32x4 apA = {0.f,0.f,0.f,0.f}, apB = {0.f,0.f,0.f,0.f};
    if (grpA) apA = *reinterpret_cast<const f32x4*>(A_p + row + o0);
    if (grpB) apB = *reinterpret_cast<const f32x4*>(A_p + row + o1);
    f32x4 adA = {0.f,0.f,0.f,0.f}, adB = {0.f,0.f,0.f,0.f};
    if (um) {
        adA = *reinterpret_cast<const f32x4*>(A_d + row + o0);
        adB = *reinterpret_cast<const f32x4*>(A_d + row + o1);
    }

    const f32x4 xbp0a = *reinterpret_cast<const f32x4*>(xbar_post + o0);
    const f32x4 xbp1a = *reinterpret_cast<const f32x4*>(xbar_post + N + o0);
    const f32x4 xbp0b = *reinterpret_cast<const f32x4*>(xbar_post + o1);
    const f32x4 xbp1b = *reinterpret_cast<const f32x4*>(xbar_post + N + o1);

    // pre-trace scalars (needed only for FMA phase)
    float xp0[D], xp1[D];
#pragma unroll
    for (int d = 0; d < D; ++d) {
        xp0[d] = xbar_pre[(size_t)(d * B + 0) * N + e];
        xp1[d] = xbar_pre[(size_t)(d * B + 1) * N + e];
    }

    // ---- 6. compute + store, iteration A ----
    {
        f32x4 pot0 = {0.f,0.f,0.f,0.f}, pot1 = {0.f,0.f,0.f,0.f};
        f32x4 dep0 = {0.f,0.f,0.f,0.f}, dep1 = {0.f,0.f,0.f,0.f};
#pragma unroll
        for (int d = 0; d < D; ++d)
#pragma unroll
            for (int j = 0; j < 4; ++j) {
                pot0[j] = fmaf(xp0[d], mA[d][j], pot0[j]);
                pot1[j] = fmaf(xp1[d], mA[d][j], pot1[j]);
                dep0[j] = fmaf(xs0[d], mA[d][j], dep0[j]);
                dep1[j] = fmaf(xs1[d], mA[d][j], dep1[j]);
            }
        f32x4 n0, n1;
#pragma unroll
        for (int j = 0; j < 4; ++j) {
            const float dw0 = xpo0a[j] * pot0[j] * apA[j] - xbp0a[j] * dep0[j] * adA[j];
            const float dw1 = xpo1a[j] * pot1[j] * apA[j] - xbp1a[j] * dep1[j] * adA[j];
            n0[j] = fminf(fmaxf(w0a[j] + dw0, 0.0f), WMAX);
            n1[j] = fminf(fmaxf(w1a[j] + dw1, 0.0f), WMAX);
        }
        __builtin_nontemporal_store(w0a, reinterpret_cast<f32x4*>(W_prev + row + o0));
        __builtin_nontemporal_store(w1a, reinterpret_cast<f32x4*>(W_prev + NN + row + o0));
        __builtin_nontemporal_store(n0, reinterpret_cast<f32x4*>(W_new + row + o0));
        __builtin_nontemporal_store(n1, reinterpret_cast<f32x4*>(W_new + NN + row + o0));
    }

    // ---- 7. compute + store, iteration B ----
    {
        f32x4 pot0 = {0.f,0.f,0.f,0.f}, pot1 = {0.f,0.f,0.f,0.f};
        f32x4 dep0 = {0.f,0.f,0.f,0.f}, dep1 = {0.f,0.f,0.f,0.f};
#pragma unroll
        for (int d = 0; d < D; ++d)
#pragma unroll
            for (int j = 0; j < 4; ++j) {
                pot0[j] = fmaf(xp0[d], mB[d][j], pot0[j]);
                pot1[j] = fmaf(xp1[d], mB[d][j], pot1[j]);
                dep0[j] = fmaf(xs0[d], mB[d][j], dep0[j]);
                dep1[j] = fmaf(xs1[d], mB[d][j], dep1[j]);
            }
        f32x4 n0, n1;
#pragma unroll
        for (int j = 0; j < 4; ++j) {
            const float dw0 = xpo0b[j] * pot0[j] * apB[j] - xbp0b[j] * dep0[j] * adB[j];
            const float dw1 = xpo1b[j] * pot1[j] * apB[j] - xbp1b[j] * dep1[j] * adB[j];
            n0[j] = fminf(fmaxf(w0b[j] + dw0, 0.0f), WMAX);
            n1[j] = fminf(fmaxf(w1b[j] + dw1, 0.0f), WMAX);
        }
        __builtin_nontemporal_store(w0b, reinterpret_cast<f32x4*>(W_prev + row + o1));
        __builtin_nontemporal_store(w1b, reinterpret_cast<f32x4*>(W_prev + NN + row + o1));
        __builtin_nontemporal_store(n0, reinterpret_cast<f32x4*>(W_new + row + o1));
        __builtin_nontemporal_store(n1, reinterpret_cast<f32x4*>(W_new + NN + row + o1));
    }

    // ---- 8. folded trace updates (off the critical path) ----
    if (tid < 16) {
        const int i = e * 16 + tid;                       // covers D*B*N = 32768
        xbar_pre_new[i] = ALPHA_P * xbar_pre[i] + (1.0f - ALPHA_P) * Xd[i];
    } else if (tid < 18) {
        const int i = e * 2 + (tid - 16);                 // covers B*N = 4096
        xbar_post_new[i] = ALPHA_D * xbar_post[i] + (1.0f - ALPHA_D) * Xpost[i];
    }
}

extern "C" void kernel_launch(void* const* d_in, const int* in_sizes, int n_in,
                              void* d_out, int out_size, void* d_ws, size_t ws_size,
                              hipStream_t stream) {
    const float* Xd        = (const float*)d_in[0];  // (D,B,N)
    const float* Xpost     = (const float*)d_in[1];  // (B,N)
    const float* xbar_pre  = (const float*)d_in[2];  // (D,B,N)
    const float* xbar_post = (const float*)d_in[3];  // (B,N)
    const float* W         = (const float*)d_in[4];  // (B,N,N)
    const float* dmap      = (const float*)d_in[5];  // (D,N,N)
    const float* A_p       = (const float*)d_in[6];  // (N,N)
    const float* A_d       = (const float*)d_in[7];  // (N,N)

    float* out = (float*)d_out;
    float* W_prev        = out;                              // B*N*N
    float* W_new         = W_prev + (size_t)B * NN;          // B*N*N
    float* xbar_pre_new  = W_new + (size_t)B * NN;           // D*B*N
    float* xbar_post_new = xbar_pre_new + (size_t)D * B * N; // B*N

    stdp_main<<<N, 256, 0, stream>>>(Xd, Xpost, xbar_pre, xbar_post, W, dmap,
                                     A_p, A_d, W_prev, W_new,
                                     xbar_pre_new, xbar_post_new);
}

// Round 8
// 46.066 us; speedup vs baseline: 2.0632x; 2.0632x over previous
//
#include <hip/hip_runtime.h>

namespace {
constexpr int D = 8;
constexpr int B = 2;
constexpr int N = 2048;
constexpr long long NN = (long long)N * N;
constexpr float ALPHA_P = 0.95f;   // pre-trace decay
constexpr float ALPHA_D = 0.90f;   // post-trace decay
constexpr float WMAX = 1.0f;
}

typedef float f32x4 __attribute__((ext_vector_type(4)));

// Grid = 2*N blocks: block = (e, half). Each block covers a contiguous
// 1024-col half-row with one R6-shaped iteration: dense 1KB-per-wave-instr
// accesses, 16B-granular exec-predicated dmap/A loads with exact-zero
// substitution (bit-identical: skipped values only ever multiply 0).
// Single short body keeps VGPR ~50 -> high occupancy (R7 lesson: the memory
// system needs many waves, not deep per-wave pipelines).
__global__ __launch_bounds__(256) void stdp_main(
    const float* __restrict__ Xd,
    const float* __restrict__ Xpost,
    const float* __restrict__ xbar_pre,
    const float* __restrict__ xbar_post,
    const float* __restrict__ W,
    const float* __restrict__ dmap,
    const float* __restrict__ A_p,
    const float* __restrict__ A_d,
    float* __restrict__ W_prev,
    float* __restrict__ W_new,
    float* __restrict__ xbar_pre_new,
    float* __restrict__ xbar_post_new)
{
    const int blk = blockIdx.x;
    const int e = blk >> 1;
    const int tid = (int)threadIdx.x;
    const long long row = (long long)e * N;
    const int o = (blk & 1) * 1024 + tid * 4;

    // ---- folded trace updates: 8 pre-trace + 1 post-trace elem per block ----
    if (tid < 8) {
        const int i = blk * 8 + tid;                      // covers D*B*N = 32768
        xbar_pre_new[i] = ALPHA_P * xbar_pre[i] + (1.0f - ALPHA_P) * Xd[i];
    } else if (tid == 8) {
        const int i = blk;                                // covers B*N = 4096
        xbar_post_new[i] = ALPHA_D * xbar_post[i] + (1.0f - ALPHA_D) * Xpost[i];
    }

    // ---- row-uniform d-contraction scalars + active-plane mask ----
    float xp0[D], xp1[D], xs0[D], xs1[D];
    unsigned um = 0;
#pragma unroll
    for (int d = 0; d < D; ++d) {
        xp0[d] = xbar_pre[(size_t)(d * B + 0) * N + e];
        xp1[d] = xbar_pre[(size_t)(d * B + 1) * N + e];
        xs0[d] = Xd[(size_t)(d * B + 0) * N + e];
        xs1[d] = Xd[(size_t)(d * B + 1) * N + e];
        if (xs0[d] != 0.0f || xs1[d] != 0.0f) um |= 1u << d;
    }

    const f32x4 xpo0 = *reinterpret_cast<const f32x4*>(Xpost + o);
    const f32x4 xpo1 = *reinterpret_cast<const f32x4*>(Xpost + N + o);
    const f32x4 xbp0 = *reinterpret_cast<const f32x4*>(xbar_post + o);
    const f32x4 xbp1 = *reinterpret_cast<const f32x4*>(xbar_post + N + o);

    // does this thread's 4-col group have any post spike? (pot needed)
    const bool grp = (xpo0[0] != 0.0f) || (xpo0[1] != 0.0f) ||
                     (xpo0[2] != 0.0f) || (xpo0[3] != 0.0f) ||
                     (xpo1[0] != 0.0f) || (xpo1[1] != 0.0f) ||
                     (xpo1[2] != 0.0f) || (xpo1[3] != 0.0f);

    // W: read once, nontemporal
    const f32x4 w0 = __builtin_nontemporal_load(
        reinterpret_cast<const f32x4*>(W + row + o));
    const f32x4 w1 = __builtin_nontemporal_load(
        reinterpret_cast<const f32x4*>(W + NN + row + o));

    // A_p only where pot can be nonzero; A_d only if row has a pre spike
    f32x4 apv = {0.f, 0.f, 0.f, 0.f};
    if (grp) apv = *reinterpret_cast<const f32x4*>(A_p + row + o);
    f32x4 adv = {0.f, 0.f, 0.f, 0.f};
    if (um)  adv = *reinterpret_cast<const f32x4*>(A_d + row + o);

    // gated dense plane loads + FMA chains
    f32x4 pot0 = {0.f,0.f,0.f,0.f}, pot1 = {0.f,0.f,0.f,0.f};
    f32x4 dep0 = {0.f,0.f,0.f,0.f}, dep1 = {0.f,0.f,0.f,0.f};
#pragma unroll
    for (int d = 0; d < D; ++d) {
        f32x4 mv = {0.f, 0.f, 0.f, 0.f};
        if (grp || ((um >> d) & 1u))
            mv = *reinterpret_cast<const f32x4*>(dmap + (size_t)d * NN + row + o);
#pragma unroll
        for (int j = 0; j < 4; ++j) {
            pot0[j] = fmaf(xp0[d], mv[j], pot0[j]);
            pot1[j] = fmaf(xp1[d], mv[j], pot1[j]);
            dep0[j] = fmaf(xs0[d], mv[j], dep0[j]);
            dep1[j] = fmaf(xs1[d], mv[j], dep1[j]);
        }
    }

    f32x4 n0, n1;
#pragma unroll
    for (int j = 0; j < 4; ++j) {
        const float dw0 = xpo0[j] * pot0[j] * apv[j] - xbp0[j] * dep0[j] * adv[j];
        const float dw1 = xpo1[j] * pot1[j] * apv[j] - xbp1[j] * dep1[j] * adv[j];
        n0[j] = fminf(fmaxf(w0[j] + dw0, 0.0f), WMAX);
        n1[j] = fminf(fmaxf(w1[j] + dw1, 0.0f), WMAX);
    }

    // dense, full-line stores (one contiguous 1KB per wave instruction)
    __builtin_nontemporal_store(w0, reinterpret_cast<f32x4*>(W_prev + row + o));
    __builtin_nontemporal_store(w1, reinterpret_cast<f32x4*>(W_prev + NN + row + o));
    __builtin_nontemporal_store(n0, reinterpret_cast<f32x4*>(W_new + row + o));
    __builtin_nontemporal_store(n1, reinterpret_cast<f32x4*>(W_new + NN + row + o));
}

extern "C" void kernel_launch(void* const* d_in, const int* in_sizes, int n_in,
                              void* d_out, int out_size, void* d_ws, size_t ws_size,
                              hipStream_t stream) {
    const float* Xd        = (const float*)d_in[0];  // (D,B,N)
    const float* Xpost     = (const float*)d_in[1];  // (B,N)
    const float* xbar_pre  = (const float*)d_in[2];  // (D,B,N)
    const float* xbar_post = (const float*)d_in[3];  // (B,N)
    const float* W         = (const float*)d_in[4];  // (B,N,N)
    const float* dmap      = (const float*)d_in[5];  // (D,N,N)
    const float* A_p       = (const float*)d_in[6];  // (N,N)
    const float* A_d       = (const float*)d_in[7];  // (N,N)

    float* out = (float*)d_out;
    float* W_prev        = out;                              // B*N*N
    float* W_new         = W_prev + (size_t)B * NN;          // B*N*N
    float* xbar_pre_new  = W_new + (size_t)B * NN;           // D*B*N
    float* xbar_post_new = xbar_pre_new + (size_t)D * B * N; // B*N

    stdp_main<<<2 * N, 256, 0, stream>>>(Xd, Xpost, xbar_pre, xbar_post, W, dmap,
                                         A_p, A_d, W_prev, W_new,
                                         xbar_pre_new, xbar_post_new);
}

// Round 9
// 45.005 us; speedup vs baseline: 2.1119x; 1.0236x over previous
//
#include <hip/hip_runtime.h>

namespace {
constexpr int D = 8;
constexpr int B = 2;
constexpr int N = 2048;
constexpr long long NN = (long long)N * N;
constexpr float ALPHA_P = 0.95f;   // pre-trace decay
constexpr float ALPHA_D = 0.90f;   // post-trace decay
constexpr float WMAX = 1.0f;
}

typedef float f32x4 __attribute__((ext_vector_type(4)));

// One block per presynaptic row e; 256 threads; o = it*1024 + tid*4 (dense
// 1KB-per-wave-instruction accesses). Lesson from R6-R8: per-lane predicated
// loads fragment wave bursts and cut memory-system efficiency from 6.2 to
// 5.2 TB/s -- worth more than the bytes they save. So: dmap and A_p are
// loaded DENSE (R1's proven shape); only A_d keeps a row-uniform (whole-wave,
// zero-fragmentation) skip when the row has no pre-spike. Bit-exact: the
// skipped A_d values only ever multiply exact zeros.
__global__ __launch_bounds__(256) void stdp_main(
    const float* __restrict__ Xd,
    const float* __restrict__ Xpost,
    const float* __restrict__ xbar_pre,
    const float* __restrict__ xbar_post,
    const float* __restrict__ W,
    const float* __restrict__ dmap,
    const float* __restrict__ A_p,
    const float* __restrict__ A_d,
    float* __restrict__ W_prev,
    float* __restrict__ W_new,
    float* __restrict__ xbar_pre_new,
    float* __restrict__ xbar_post_new)
{
    const int e = blockIdx.x;
    const int tid = (int)threadIdx.x;
    const long long row = (long long)e * N;

    // ---- folded trace updates (18 elems per block) ----
    if (tid < 16) {
        const int i = e * 16 + tid;                       // covers D*B*N = 32768
        xbar_pre_new[i] = ALPHA_P * xbar_pre[i] + (1.0f - ALPHA_P) * Xd[i];
    } else if (tid < 18) {
        const int i = e * 2 + (tid - 16);                 // covers B*N = 4096
        xbar_post_new[i] = ALPHA_D * xbar_post[i] + (1.0f - ALPHA_D) * Xpost[i];
    }

    // ---- row-uniform d-contraction scalars + pre-spike mask ----
    float xp0[D], xp1[D], xs0[D], xs1[D];
    unsigned um = 0;
#pragma unroll
    for (int d = 0; d < D; ++d) {
        xp0[d] = xbar_pre[(size_t)(d * B + 0) * N + e];
        xp1[d] = xbar_pre[(size_t)(d * B + 1) * N + e];
        xs0[d] = Xd[(size_t)(d * B + 0) * N + e];
        xs1[d] = Xd[(size_t)(d * B + 1) * N + e];
        if (xs0[d] != 0.0f || xs1[d] != 0.0f) um |= 1u << d;
    }

#pragma unroll
    for (int it = 0; it < N / (256 * 4); ++it) {
        const int o = it * 1024 + tid * 4;

        const f32x4 xpo0 = *reinterpret_cast<const f32x4*>(Xpost + o);
        const f32x4 xpo1 = *reinterpret_cast<const f32x4*>(Xpost + N + o);
        const f32x4 xbp0 = *reinterpret_cast<const f32x4*>(xbar_post + o);
        const f32x4 xbp1 = *reinterpret_cast<const f32x4*>(xbar_post + N + o);

        // W: read once, nontemporal
        const f32x4 w0 = __builtin_nontemporal_load(
            reinterpret_cast<const f32x4*>(W + row + o));
        const f32x4 w1 = __builtin_nontemporal_load(
            reinterpret_cast<const f32x4*>(W + NN + row + o));

        // A_p dense; A_d gated row-uniformly (whole-wave branch, no holes)
        const f32x4 apv = *reinterpret_cast<const f32x4*>(A_p + row + o);
        f32x4 adv = {0.f, 0.f, 0.f, 0.f};
        if (um)
            adv = *reinterpret_cast<const f32x4*>(A_d + row + o);

        // dense plane loads + FMA chains
        f32x4 pot0 = {0.f,0.f,0.f,0.f}, pot1 = {0.f,0.f,0.f,0.f};
        f32x4 dep0 = {0.f,0.f,0.f,0.f}, dep1 = {0.f,0.f,0.f,0.f};
#pragma unroll
        for (int d = 0; d < D; ++d) {
            const f32x4 mv =
                *reinterpret_cast<const f32x4*>(dmap + (size_t)d * NN + row + o);
#pragma unroll
            for (int j = 0; j < 4; ++j) {
                pot0[j] = fmaf(xp0[d], mv[j], pot0[j]);
                pot1[j] = fmaf(xp1[d], mv[j], pot1[j]);
                dep0[j] = fmaf(xs0[d], mv[j], dep0[j]);
                dep1[j] = fmaf(xs1[d], mv[j], dep1[j]);
            }
        }

        f32x4 n0, n1;
#pragma unroll
        for (int j = 0; j < 4; ++j) {
            const float dw0 = xpo0[j] * pot0[j] * apv[j] - xbp0[j] * dep0[j] * adv[j];
            const float dw1 = xpo1[j] * pot1[j] * apv[j] - xbp1[j] * dep1[j] * adv[j];
            n0[j] = fminf(fmaxf(w0[j] + dw0, 0.0f), WMAX);
            n1[j] = fminf(fmaxf(w1[j] + dw1, 0.0f), WMAX);
        }

        // dense, full-line stores (one contiguous 1KB per wave instruction)
        __builtin_nontemporal_store(w0, reinterpret_cast<f32x4*>(W_prev + row + o));
        __builtin_nontemporal_store(w1, reinterpret_cast<f32x4*>(W_prev + NN + row + o));
        __builtin_nontemporal_store(n0, reinterpret_cast<f32x4*>(W_new + row + o));
        __builtin_nontemporal_store(n1, reinterpret_cast<f32x4*>(W_new + NN + row + o));
    }
}

extern "C" void kernel_launch(void* const* d_in, const int* in_sizes, int n_in,
                              void* d_out, int out_size, void* d_ws, size_t ws_size,
                              hipStream_t stream) {
    const float* Xd        = (const float*)d_in[0];  // (D,B,N)
    const float* Xpost     = (const float*)d_in[1];  // (B,N)
    const float* xbar_pre  = (const float*)d_in[2];  // (D,B,N)
    const float* xbar_post = (const float*)d_in[3];  // (B,N)
    const float* W         = (const float*)d_in[4];  // (B,N,N)
    const float* dmap      = (const float*)d_in[5];  // (D,N,N)
    const float* A_p       = (const float*)d_in[6];  // (N,N)
    const float* A_d       = (const float*)d_in[7];  // (N,N)

    float* out = (float*)d_out;
    float* W_prev        = out;                              // B*N*N
    float* W_new         = W_prev + (size_t)B * NN;          // B*N*N
    float* xbar_pre_new  = W_new + (size_t)B * NN;           // D*B*N
    float* xbar_post_new = xbar_pre_new + (size_t)D * B * N; // B*N

    stdp_main<<<N, 256, 0, stream>>>(Xd, Xpost, xbar_pre, xbar_post, W, dmap,
                                     A_p, A_d, W_prev, W_new,
                                     xbar_pre_new, xbar_post_new);
}